// Round 6
// baseline (631.715 us; speedup 1.0000x reference)
//
#include <hip/hip_runtime.h>

// DeformConv2d forward, fp32. B=8, C=64, H=W=128, N=9 (3x3), OC=128, pad=1.
//
// ws layout (floats):
//   wT  : [576][20]        offset-conv weights transposed (uniform reads)  11520
//   wP  : [c*9+n][o]       main weights, o-contiguous                      73728
//   off : [b][9][HW][2]    offsets (ox,oy) incl. bias                    2359296
// total = 2,444,544 floats = 9.78 MB

#define HW    16384
#define CIN   64
#define OC    128

constexpr int WT_OFF  = 0;
constexpr int WP_OFF  = 11520;
constexpr int OFF_OFF = WP_OFF + 73728;   // 85248

__device__ __forceinline__ float clamp129(float v) {
  return fminf(fmaxf(v, 0.f), 129.f);
}

// Bilinear params for kernel point n at output pixel (row,col), offset (ox,oy).
// Exact reference semantics: coords in the 130x130 padded frame, clip to
// [0,129]; pad cells (outside 1..128) contribute zero, folded into g=0 so the
// gather itself is unconditional.
__device__ __forceinline__ void bilin_params(int row, int col, int n,
                                             float ox, float oy,
                                             float4& g, int4& idx) {
  float px = (float)(row + n / 3 - 1) + ox;
  float py = (float)(col + n % 3 - 1) + oy;
  float fx = floorf(px), fy = floorf(py);
  float qltx = clamp129(fx),       qlty = clamp129(fy);
  float qrbx = clamp129(fx + 1.f), qrby = clamp129(fy + 1.f);
  float pcx = clamp129(px),        pcy = clamp129(py);
  float dltx = 1.f + qltx - pcx, dlty = 1.f + qlty - pcy;
  float drbx = 1.f - qrbx + pcx, drby = 1.f - qrby + pcy;
  float gg[4] = {dltx * dlty, drbx * drby, dltx * drby, drbx * dlty};
  int rr[4]   = {(int)qltx, (int)qrbx, (int)qltx, (int)qrbx};
  int cc[4]   = {(int)qlty, (int)qrby, (int)qrby, (int)qlty};
  int ii[4];
#pragma unroll
  for (int k = 0; k < 4; ++k) {
    bool v = (rr[k] >= 1) && (rr[k] <= 128) && (cc[k] >= 1) && (cc[k] <= 128);
    ii[k] = v ? ((rr[k] - 1) * 128 + (cc[k] - 1)) : 0;
    if (!v) gg[k] = 0.f;
  }
  g   = make_float4(gg[0], gg[1], gg[2], gg[3]);
  idx = make_int4(ii[0], ii[1], ii[2], ii[3]);
}

// ---------------- kernel 0: weight repack ----------------
__global__ __launch_bounds__(256) void repack_kernel(
    const float* __restrict__ w_conv, const float* __restrict__ w_p,
    float* __restrict__ wP, float* __restrict__ wT) {
  int i = blockIdx.x * 256 + threadIdx.x;
  if (i < 73728) {
    int o = i & 127, m = i >> 7;   // wP[m*128+o] = w_conv[o*576+m]
    wP[i] = w_conv[o * 576 + m];
  }
  int j = i - 73728;
  if (j >= 0 && j < 11520) {
    int m = j / 20, n2 = j - m * 20;  // wT[m*20+n2] = w_p[n2*576+m]
    wT[j] = (n2 < 18) ? w_p[n2 * 576 + m] : 0.f;
  }
}

// ---------------- kernel 1: offset conv ----------------
__global__ __launch_bounds__(256) void offs_kernel(
    const float* __restrict__ x, const float* __restrict__ wT,
    const float* __restrict__ b_p, float* __restrict__ off) {
  const int b   = blockIdx.y;
  const int hw  = blockIdx.x * 256 + threadIdx.x;
  const int row = hw >> 7;
  const int w   = hw & 127;

  float acc[18];
#pragma unroll
  for (int i = 0; i < 18; ++i) acc[i] = 0.f;

  const float* xb = x + b * (CIN * HW);
  for (int ci = 0; ci < CIN; ++ci) {
    const float* xs = xb + ci * HW;
#pragma unroll
    for (int kh = 0; kh < 3; ++kh) {
      int r = row + kh - 1;
      bool vr = (unsigned)r < 128u;
      int base = r * 128 + w;
      float rbv[3];
      rbv[0] = (vr && w >= 1)   ? xs[base - 1] : 0.f;
      rbv[1] = vr               ? xs[base]     : 0.f;
      rbv[2] = (vr && w <= 126) ? xs[base + 1] : 0.f;
#pragma unroll
      for (int kw = 0; kw < 3; ++kw) {
        const float* wr = wT + (ci * 9 + kh * 3 + kw) * 20;  // wave-uniform
        float xv = rbv[kw];
#pragma unroll
        for (int n2 = 0; n2 < 18; ++n2)
          acc[n2] = fmaf(xv, wr[n2], acc[n2]);
      }
    }
  }

#pragma unroll
  for (int n = 0; n < 9; ++n) {
    float2 o2 = make_float2(acc[n] + b_p[n], acc[n + 9] + b_p[n + 9]);
    *(float2*)(off + ((b * 9 + n) * HW + hw) * 2) = o2;
  }
}

// ---------------- kernel 2: gather + implicit GEMM ----------------
// block: 64 hw x 128 o, 256 threads, acc 8o x 4hw per thread.
__global__ __launch_bounds__(256) void main_kernel(
    const float* __restrict__ x, const float* __restrict__ wP,
    const float* __restrict__ off, float* __restrict__ out) {
  __shared__ __align__(16) float xlds[8 * 9 * 64];  // [c][n][hwi] = c*576+n*64+hwi

  const int b      = blockIdx.y;
  const int hwbase = blockIdx.x * 64;
  const int tid    = threadIdx.x;
  const int hwg    = tid & 15;   // 16 pixel-groups of 4
  const int og     = tid >> 4;   // 16 output-groups of 8
  const int o0     = og * 8;
  const bool has3  = (tid < 64); // 576 (n,hw) pairs over 256 threads

  float4 g0, g1, g2 = make_float4(0.f, 0.f, 0.f, 0.f);
  int4   i0, i1, i2 = make_int4(0, 0, 0, 0);
  {
    int p = tid, n = p >> 6, hw = hwbase + (p & 63);
    float2 ov = *(const float2*)(off + ((b * 9 + n) * HW + hw) * 2);
    bilin_params(hw >> 7, hw & 127, n, ov.x, ov.y, g0, i0);
    p = tid + 256; n = p >> 6; hw = hwbase + (p & 63);
    ov = *(const float2*)(off + ((b * 9 + n) * HW + hw) * 2);
    bilin_params(hw >> 7, hw & 127, n, ov.x, ov.y, g1, i1);
    if (has3) {
      p = tid + 512; n = p >> 6; hw = hwbase + (p & 63);
      ov = *(const float2*)(off + ((b * 9 + n) * HW + hw) * 2);
      bilin_params(hw >> 7, hw & 127, n, ov.x, ov.y, g2, i2);
    }
  }

  float acc[8][4];
#pragma unroll
  for (int oi = 0; oi < 8; ++oi)
#pragma unroll
    for (int p2 = 0; p2 < 4; ++p2) acc[oi][p2] = 0.f;

  const float* xb = x + b * (CIN * HW);

  for (int cc = 0; cc < 8; ++cc) {
    const int c0 = cc * 8;
    __syncthreads();  // prev chunk fully consumed
    // ---- gather phase: x_off[c][n][hwi] for this channel chunk ----
#pragma unroll
    for (int c = 0; c < 8; ++c) {
      const float* xc = xb + (c0 + c) * HW;
      float v0 = g0.x * xc[i0.x] + g0.y * xc[i0.y] +
                 g0.z * xc[i0.z] + g0.w * xc[i0.w];
      xlds[c * 576 + tid] = v0;
      float v1 = g1.x * xc[i1.x] + g1.y * xc[i1.y] +
                 g1.z * xc[i1.z] + g1.w * xc[i1.w];
      xlds[c * 576 + tid + 256] = v1;
      if (has3) {
        float v2 = g2.x * xc[i2.x] + g2.y * xc[i2.y] +
                   g2.z * xc[i2.z] + g2.w * xc[i2.w];
        xlds[c * 576 + tid + 512] = v2;
      }
    }
    __syncthreads();
    // ---- GEMM phase: rank-1 updates over (c, n) ----
#pragma unroll
    for (int c = 0; c < 8; ++c) {
#pragma unroll
      for (int n = 0; n < 9; ++n) {
        const float4 xv = *(const float4*)&xlds[c * 576 + n * 64 + hwg * 4];
        const float* wrow = wP + ((c0 + c) * 9 + n) * 128 + o0;
        const float4 wa = *(const float4*)wrow;
        const float4 wb = *(const float4*)(wrow + 4);
        float wv[8]  = {wa.x, wa.y, wa.z, wa.w, wb.x, wb.y, wb.z, wb.w};
        float xvv[4] = {xv.x, xv.y, xv.z, xv.w};
#pragma unroll
        for (int oi = 0; oi < 8; ++oi)
#pragma unroll
          for (int p2 = 0; p2 < 4; ++p2)
            acc[oi][p2] = fmaf(wv[oi], xvv[p2], acc[oi][p2]);
      }
    }
  }

#pragma unroll
  for (int oi = 0; oi < 8; ++oi) {
    int base = (b * OC + o0 + oi) * HW + hwbase + hwg * 4;
    *(float4*)(out + base) =
        make_float4(acc[oi][0], acc[oi][1], acc[oi][2], acc[oi][3]);
  }
}

extern "C" void kernel_launch(void* const* d_in, const int* in_sizes, int n_in,
                              void* d_out, int out_size, void* d_ws, size_t ws_size,
                              hipStream_t stream) {
  const float* x      = (const float*)d_in[0];  // (8,64,128,128)
  const float* w_conv = (const float*)d_in[1];  // (128,64,3,3)
  const float* w_p    = (const float*)d_in[2];  // (18,64,3,3)
  const float* b_p    = (const float*)d_in[3];  // (18,)
  float* outp = (float*)d_out;                  // (8,128,128,128)
  float* ws   = (float*)d_ws;                   // needs >= 9.78 MB

  float* wT  = ws + WT_OFF;
  float* wP  = ws + WP_OFF;
  float* off = ws + OFF_OFF;

  repack_kernel<<<333, 256, 0, stream>>>(w_conv, w_p, wP, wT);
  offs_kernel<<<dim3(64, 8), 256, 0, stream>>>(x, wT, b_p, off);
  main_kernel<<<dim3(256, 8), 256, 0, stream>>>(x, wP, off, outp);
}

// Round 7
// 610.144 us; speedup vs baseline: 1.0354x; 1.0354x over previous
//
#include <hip/hip_runtime.h>

// DeformConv2d forward, fp32. B=8, C=64, H=W=128, N=9 (3x3), OC=128, pad=1.
//
// R7: (1) main_kernel barrier-free: per-wave private LDS tiles, lgkmcnt-only
//     sync -> waves drift, gather latency hides under other waves' GEMM.
//     (2) offs_kernel c-split x2 (blockIdx.z) for 2x occupancy; main sums
//     the two partial offset fields + bias in its prologue.
//
// ws layout (floats):
//   wT   : [576][20]          offset-conv weights transposed          11520
//   wP   : [c*9+n][o]         main weights, o-contiguous              73728
//   offp : [2][b][9][HW][2]   partial offsets (c-halves)            4718592
// total = 4,803,840 floats = 19.2 MB

#define HW    16384
#define CIN   64
#define OC    128

constexpr int WT_OFF  = 0;
constexpr int WP_OFF  = 11520;
constexpr int OFF_OFF = WP_OFF + 73728;        // 85248
constexpr int OFF_HALF = 8 * 9 * HW * 2;       // floats per half

__device__ __forceinline__ float clamp129(float v) {
  return fminf(fmaxf(v, 0.f), 129.f);
}

// Bilinear params for kernel point n at output pixel (row,col), offset (ox,oy).
// Reference semantics: coords in the 130x130 padded frame, clip to [0,129];
// pad cells (outside 1..128) contribute zero, folded into g=0.
__device__ __forceinline__ void bilin_params(int row, int col, int n,
                                             float ox, float oy,
                                             float4& g, int4& idx) {
  float px = (float)(row + n / 3 - 1) + ox;
  float py = (float)(col + n % 3 - 1) + oy;
  float fx = floorf(px), fy = floorf(py);
  float qltx = clamp129(fx),       qlty = clamp129(fy);
  float qrbx = clamp129(fx + 1.f), qrby = clamp129(fy + 1.f);
  float pcx = clamp129(px),        pcy = clamp129(py);
  float dltx = 1.f + qltx - pcx, dlty = 1.f + qlty - pcy;
  float drbx = 1.f - qrbx + pcx, drby = 1.f - qrby + pcy;
  float gg[4] = {dltx * dlty, drbx * drby, dltx * drby, drbx * dlty};
  int rr[4]   = {(int)qltx, (int)qrbx, (int)qltx, (int)qrbx};
  int cc[4]   = {(int)qlty, (int)qrby, (int)qrby, (int)qlty};
  int ii[4];
#pragma unroll
  for (int k = 0; k < 4; ++k) {
    bool v = (rr[k] >= 1) && (rr[k] <= 128) && (cc[k] >= 1) && (cc[k] <= 128);
    ii[k] = v ? ((rr[k] - 1) * 128 + (cc[k] - 1)) : 0;
    if (!v) gg[k] = 0.f;
  }
  g   = make_float4(gg[0], gg[1], gg[2], gg[3]);
  idx = make_int4(ii[0], ii[1], ii[2], ii[3]);
}

// ---------------- kernel 0: weight repack ----------------
__global__ __launch_bounds__(256) void repack_kernel(
    const float* __restrict__ w_conv, const float* __restrict__ w_p,
    float* __restrict__ wP, float* __restrict__ wT) {
  int i = blockIdx.x * 256 + threadIdx.x;
  if (i < 73728) {
    int o = i & 127, m = i >> 7;   // wP[m*128+o] = w_conv[o*576+m]
    wP[i] = w_conv[o * 576 + m];
  }
  int j = i - 73728;
  if (j >= 0 && j < 11520) {
    int m = j / 20, n2 = j - m * 20;  // wT[m*20+n2] = w_p[n2*576+m]
    wT[j] = (n2 < 18) ? w_p[n2 * 576 + m] : 0.f;
  }
}

// ---------------- kernel 1: offset conv, c-split x2 ----------------
__global__ __launch_bounds__(256) void offs_kernel(
    const float* __restrict__ x, const float* __restrict__ wT,
    float* __restrict__ offp) {
  const int half = blockIdx.z;          // c in [half*32, half*32+32)
  const int b    = blockIdx.y;
  const int hw   = blockIdx.x * 256 + threadIdx.x;
  const int row  = hw >> 7;
  const int w    = hw & 127;

  float acc[18];
#pragma unroll
  for (int i = 0; i < 18; ++i) acc[i] = 0.f;

  const float* xb = x + b * (CIN * HW);
  const int c0 = half * 32;
  for (int ci = c0; ci < c0 + 32; ++ci) {
    const float* xs = xb + ci * HW;
#pragma unroll
    for (int kh = 0; kh < 3; ++kh) {
      int r = row + kh - 1;
      bool vr = (unsigned)r < 128u;
      int base = r * 128 + w;
      float rbv[3];
      rbv[0] = (vr && w >= 1)   ? xs[base - 1] : 0.f;
      rbv[1] = vr               ? xs[base]     : 0.f;
      rbv[2] = (vr && w <= 126) ? xs[base + 1] : 0.f;
#pragma unroll
      for (int kw = 0; kw < 3; ++kw) {
        const float* wr = wT + (ci * 9 + kh * 3 + kw) * 20;  // wave-uniform
        float xv = rbv[kw];
#pragma unroll
        for (int n2 = 0; n2 < 18; ++n2)
          acc[n2] = fmaf(xv, wr[n2], acc[n2]);
      }
    }
  }

  float* dst = offp + half * OFF_HALF;
#pragma unroll
  for (int n = 0; n < 9; ++n) {
    *(float2*)(dst + ((b * 9 + n) * HW + hw) * 2) =
        make_float2(acc[n], acc[n + 9]);
  }
}

// ---------------- kernel 2: gather + implicit GEMM, barrier-free ----------
// block: 256 threads = 4 waves; each wave owns 16 hw x 128 o and a private
// 1152-float LDS tile [c8][n9][hw16]. No __syncthreads anywhere.
__global__ __launch_bounds__(256) void main_kernel(
    const float* __restrict__ x, const float* __restrict__ wP,
    const float* __restrict__ offp, const float* __restrict__ b_p,
    float* __restrict__ out) {
  __shared__ __align__(16) float xlds[4 * 1152];

  const int b     = blockIdx.y;
  const int tid   = threadIdx.x;
  const int wv    = tid >> 6;
  const int lane  = tid & 63;
  const int hw0   = blockIdx.x * 64 + wv * 16;  // wave's 16 pixels
  const int wbase = wv * 1152;
  const int hwg2  = lane & 3;    // 4 hw-quads
  const int og2   = lane >> 2;   // 16 o-groups of 8
  const int o0    = og2 * 8;
  const bool has3 = (lane < 16); // 144 (n,hwi) items over 64 lanes: 2 or 3

  // --- per-lane bilinear params for items t = lane, lane+64, lane+128 ---
  float4 g0, g1, g2 = make_float4(0.f, 0.f, 0.f, 0.f);
  int4   i0, i1, i2 = make_int4(0, 0, 0, 0);
  {
    const float* oh0 = offp;
    const float* oh1 = offp + OFF_HALF;
#pragma unroll
    for (int j = 0; j < 3; ++j) {
      if (j == 2 && !has3) break;
      int t = lane + j * 64;        // t in [0,144): n = t/16, hwi = t%16
      int n = t >> 4, hw = hw0 + (t & 15);
      int oidx = ((b * 9 + n) * HW + hw) * 2;
      float2 pa = *(const float2*)(oh0 + oidx);
      float2 pb = *(const float2*)(oh1 + oidx);
      float ox = pa.x + pb.x + b_p[n];
      float oy = pa.y + pb.y + b_p[n + 9];
      float4 g; int4 ii;
      bilin_params(hw >> 7, hw & 127, n, ox, oy, g, ii);
      if (j == 0) { g0 = g; i0 = ii; }
      else if (j == 1) { g1 = g; i1 = ii; }
      else { g2 = g; i2 = ii; }
    }
  }

  float acc[8][4];
#pragma unroll
  for (int oi = 0; oi < 8; ++oi)
#pragma unroll
    for (int p2 = 0; p2 < 4; ++p2) acc[oi][p2] = 0.f;

  const float* xb = x + b * (CIN * HW);

  for (int cc = 0; cc < 8; ++cc) {
    const int c0 = cc * 8;
    // ---- gather phase: wave-private, x_off[c][n][hwi] ----
#pragma unroll
    for (int c = 0; c < 8; ++c) {
      const float* xc = xb + (c0 + c) * HW;
      float v0 = g0.x * xc[i0.x] + g0.y * xc[i0.y] +
                 g0.z * xc[i0.z] + g0.w * xc[i0.w];
      xlds[wbase + c * 144 + lane] = v0;
      float v1 = g1.x * xc[i1.x] + g1.y * xc[i1.y] +
                 g1.z * xc[i1.z] + g1.w * xc[i1.w];
      xlds[wbase + c * 144 + 64 + lane] = v1;
      if (has3) {
        float v2 = g2.x * xc[i2.x] + g2.y * xc[i2.y] +
                   g2.z * xc[i2.z] + g2.w * xc[i2.w];
        xlds[wbase + c * 144 + 128 + lane] = v2;
      }
    }
    // wave-level sync: all ds_writes of THIS wave complete (DS is in-order
    // per wave; wave64 lockstep means no cross-wave traffic to wait for).
    asm volatile("s_waitcnt lgkmcnt(0)" ::: "memory");
    // ---- GEMM phase: rank-1 updates over (c, n) ----
#pragma unroll
    for (int c = 0; c < 8; ++c) {
#pragma unroll
      for (int n = 0; n < 9; ++n) {
        const float4 xv =
            *(const float4*)&xlds[wbase + c * 144 + n * 16 + hwg2 * 4];
        const float* wrow = wP + ((c0 + c) * 9 + n) * 128 + o0;
        const float4 wa = *(const float4*)wrow;
        const float4 wb = *(const float4*)(wrow + 4);
        float wv[8]  = {wa.x, wa.y, wa.z, wa.w, wb.x, wb.y, wb.z, wb.w};
        float xvv[4] = {xv.x, xv.y, xv.z, xv.w};
#pragma unroll
        for (int oi = 0; oi < 8; ++oi)
#pragma unroll
          for (int p2 = 0; p2 < 4; ++p2)
            acc[oi][p2] = fmaf(wv[oi], xvv[p2], acc[oi][p2]);
      }
    }
    // compiler fence: keep next chunk's ds_writes after this chunk's reads
    // (HW side is safe: DS ops execute in order within a wave).
    asm volatile("" ::: "memory");
  }

#pragma unroll
  for (int oi = 0; oi < 8; ++oi) {
    int base = (b * OC + o0 + oi) * HW + hw0 + hwg2 * 4;
    *(float4*)(out + base) =
        make_float4(acc[oi][0], acc[oi][1], acc[oi][2], acc[oi][3]);
  }
}

extern "C" void kernel_launch(void* const* d_in, const int* in_sizes, int n_in,
                              void* d_out, int out_size, void* d_ws, size_t ws_size,
                              hipStream_t stream) {
  const float* x      = (const float*)d_in[0];  // (8,64,128,128)
  const float* w_conv = (const float*)d_in[1];  // (128,64,3,3)
  const float* w_p    = (const float*)d_in[2];  // (18,64,3,3)
  const float* b_p    = (const float*)d_in[3];  // (18,)
  float* outp = (float*)d_out;                  // (8,128,128,128)
  float* ws   = (float*)d_ws;                   // needs >= 19.2 MB

  float* wT   = ws + WT_OFF;
  float* wP   = ws + WP_OFF;
  float* offp = ws + OFF_OFF;

  repack_kernel<<<333, 256, 0, stream>>>(w_conv, w_p, wP, wT);
  offs_kernel<<<dim3(64, 8, 2), 256, 0, stream>>>(x, wT, offp);
  main_kernel<<<dim3(256, 8), 256, 0, stream>>>(x, wP, offp, b_p, outp);
}

// Round 8
// 479.918 us; speedup vs baseline: 1.3163x; 1.2714x over previous
//
#include <hip/hip_runtime.h>

// DeformConv2d forward, fp32. B=8, C=64, H=W=128, N=9 (3x3), OC=128, pad=1.
//
// v5: (1) x transposed to NHWC (xT[b][hw][c]) -> bilinear gather loads are
//     contiguous float4 per corner per 8-channel chunk (4x fewer VMEM instrs,
//     1 line each). (2) main waves are o-sliced: wave w owns o[32w,32w+32) for
//     ALL 64 block pixels -> weight addresses wave-uniform -> scalar s_load
//     path, off the vector-memory pipe. (3) gather is block-cooperative into
//     LDS, shared by the 4 o-waves.
//
// ws layout (floats):
//   wT   : [576][20]          offset-conv weights^T                    11520
//   wP   : [n*64+c][o]        main weights, o-contiguous               73728
//   offp : [2][b][9][HW][2]   partial offsets (c-halves)             4718592
//   xT   : [b][hw][c]         NHWC input                             8388608
// total = 13,192,448 floats = 52.8 MB

#define HW    16384
#define CIN   64
#define OC    128

constexpr int WT_OFF   = 0;
constexpr int WP_OFF   = 11520;
constexpr int OFF_OFF  = WP_OFF + 73728;           // 85248
constexpr int OFF_HALF = 8 * 9 * HW * 2;           // 2359296
constexpr int XT_OFF   = OFF_OFF + 2 * OFF_HALF;   // 4803840

__device__ __forceinline__ float clamp129(float v) {
  return fminf(fmaxf(v, 0.f), 129.f);
}

// Bilinear params, exact reference semantics (130x130 padded frame, clip to
// [0,129]; pad cells contribute zero -> folded into g=0).
__device__ __forceinline__ void bilin_params(int row, int col, int n,
                                             float ox, float oy,
                                             float4& g, int4& idx) {
  float px = (float)(row + n / 3 - 1) + ox;
  float py = (float)(col + n % 3 - 1) + oy;
  float fx = floorf(px), fy = floorf(py);
  float qltx = clamp129(fx),       qlty = clamp129(fy);
  float qrbx = clamp129(fx + 1.f), qrby = clamp129(fy + 1.f);
  float pcx = clamp129(px),        pcy = clamp129(py);
  float dltx = 1.f + qltx - pcx, dlty = 1.f + qlty - pcy;
  float drbx = 1.f - qrbx + pcx, drby = 1.f - qrby + pcy;
  float gg[4] = {dltx * dlty, drbx * drby, dltx * drby, drbx * dlty};
  int rr[4]   = {(int)qltx, (int)qrbx, (int)qltx, (int)qrbx};
  int cc[4]   = {(int)qlty, (int)qrby, (int)qrby, (int)qlty};
  int ii[4];
#pragma unroll
  for (int k = 0; k < 4; ++k) {
    bool v = (rr[k] >= 1) && (rr[k] <= 128) && (cc[k] >= 1) && (cc[k] <= 128);
    ii[k] = v ? ((rr[k] - 1) * 128 + (cc[k] - 1)) : 0;
    if (!v) gg[k] = 0.f;
  }
  g   = make_float4(gg[0], gg[1], gg[2], gg[3]);
  idx = make_int4(ii[0], ii[1], ii[2], ii[3]);
}

// ---------------- kernel 0: weight repack ----------------
__global__ __launch_bounds__(256) void repack_kernel(
    const float* __restrict__ w_conv, const float* __restrict__ w_p,
    float* __restrict__ wP, float* __restrict__ wT) {
  int i = blockIdx.x * 256 + threadIdx.x;
  if (i < 73728) {
    // wP[(n*64+c)*128 + o] = w_conv[o][c][n]
    int o = i & 127, m = i >> 7, n = m >> 6, c = m & 63;
    wP[i] = w_conv[o * 576 + c * 9 + n];
  }
  int j = i - 73728;
  if (j >= 0 && j < 11520) {
    int m = j / 20, n2 = j - m * 20;  // wT[m*20+n2] = w_p[n2*576+m]
    wT[j] = (n2 < 18) ? w_p[n2 * 576 + m] : 0.f;
  }
}

// ---------------- kernel 1: NCHW -> NHWC transpose ----------------
__global__ __launch_bounds__(256) void transpose_kernel(
    const float* __restrict__ x, float* __restrict__ xT) {
  __shared__ float t[64][65];
  const int b   = blockIdx.y;
  const int hw0 = blockIdx.x * 64;
  const int tid = threadIdx.x;
  {
    const int hwi = tid & 63, cq = tid >> 6;
    const float* xb = x + b * (CIN * HW);
#pragma unroll
    for (int k = 0; k < 16; ++k) {
      int c = cq * 16 + k;
      t[hwi][c] = xb[c * HW + hw0 + hwi];   // coalesced over hwi
    }
  }
  __syncthreads();
  {
    const int ci = tid & 63, hq = tid >> 6;
    float* xTb = xT + ((size_t)b * HW + hw0) * CIN;
#pragma unroll
    for (int k = 0; k < 16; ++k) {
      int hwi = hq * 16 + k;
      xTb[hwi * CIN + ci] = t[hwi][ci];     // coalesced over ci
    }
  }
}

// ---------------- kernel 2: offset conv, c-split x2 ----------------
__global__ __launch_bounds__(256) void offs_kernel(
    const float* __restrict__ x, const float* __restrict__ wT,
    float* __restrict__ offp) {
  const int half = blockIdx.z;
  const int b    = blockIdx.y;
  const int hw   = blockIdx.x * 256 + threadIdx.x;
  const int row  = hw >> 7;
  const int w    = hw & 127;

  float acc[18];
#pragma unroll
  for (int i = 0; i < 18; ++i) acc[i] = 0.f;

  const float* xb = x + b * (CIN * HW);
  const int c0 = half * 32;
  for (int ci = c0; ci < c0 + 32; ++ci) {
    const float* xs = xb + ci * HW;
#pragma unroll
    for (int kh = 0; kh < 3; ++kh) {
      int r = row + kh - 1;
      bool vr = (unsigned)r < 128u;
      int base = r * 128 + w;
      float rbv[3];
      rbv[0] = (vr && w >= 1)   ? xs[base - 1] : 0.f;
      rbv[1] = vr               ? xs[base]     : 0.f;
      rbv[2] = (vr && w <= 126) ? xs[base + 1] : 0.f;
#pragma unroll
      for (int kw = 0; kw < 3; ++kw) {
        const float* wr = wT + (ci * 9 + kh * 3 + kw) * 20;  // wave-uniform
        float xv = rbv[kw];
#pragma unroll
        for (int n2 = 0; n2 < 18; ++n2)
          acc[n2] = fmaf(xv, wr[n2], acc[n2]);
      }
    }
  }

  float* dst = offp + half * OFF_HALF;
#pragma unroll
  for (int n = 0; n < 9; ++n) {
    *(float2*)(dst + ((b * 9 + n) * HW + hw) * 2) =
        make_float2(acc[n], acc[n + 9]);
  }
}

// ---------------- kernel 3: gather + o-sliced GEMM ----------------
// block: 64 px, 256 threads = 4 waves; wave w computes o in [32w, 32w+32)
// for all 64 px (acc[32] per lane, lane = px). Gather is block-cooperative:
// 576 (n,px) items, NHWC float4 corner loads, staged to LDS [c8][n9][px64].
__global__ __launch_bounds__(256) void main_kernel(
    const float* __restrict__ xT, const float* __restrict__ wP,
    const float* __restrict__ offp, const float* __restrict__ b_p,
    float* __restrict__ out) {
  __shared__ __align__(16) float xlds[8 * 576];

  const int b    = blockIdx.y;
  const int px0  = blockIdx.x * 64;
  const int tid  = threadIdx.x;
  const int lane = tid & 63;
  const bool has3 = (tid < 64);  // 576 items over 256 threads: 2 or 3 each

  // wave-uniform o-slice base (readfirstlane -> SGPR -> scalar weight loads)
  const int ow_u = __builtin_amdgcn_readfirstlane((tid >> 6) * 32);
  const float* __restrict__ wPu = wP + ow_u;

  // --- per-thread bilinear params for items t = tid, tid+256, tid+512 ---
  float4 g0, g1, g2 = make_float4(0.f, 0.f, 0.f, 0.f);
  int4   i0, i1, i2 = make_int4(0, 0, 0, 0);
  {
    const float* oh0 = offp;
    const float* oh1 = offp + OFF_HALF;
#pragma unroll
    for (int j = 0; j < 3; ++j) {
      if (j == 2 && !has3) break;
      int t = tid + j * 256;          // n = t>>6, pxi = t&63
      int n = t >> 6, hw = px0 + (t & 63);
      int oidx = ((b * 9 + n) * HW + hw) * 2;
      float2 pa = *(const float2*)(oh0 + oidx);
      float2 pb = *(const float2*)(oh1 + oidx);
      float ox = pa.x + pb.x + b_p[n];
      float oy = pa.y + pb.y + b_p[n + 9];
      float4 g; int4 ii;
      bilin_params(hw >> 7, hw & 127, n, ox, oy, g, ii);
      if (j == 0) { g0 = g; i0 = ii; }
      else if (j == 1) { g1 = g; i1 = ii; }
      else { g2 = g; i2 = ii; }
    }
  }

  float acc[32];
#pragma unroll
  for (int k = 0; k < 32; ++k) acc[k] = 0.f;

  const float* xTb = xT + (size_t)b * HW * CIN;

// gather one item (8 channels c0..c0+7) from NHWC via 4 corner float4-pairs
#define GATH(G, I, POS)                                                    \
  {                                                                        \
    const float* pa = xTb + (I).x * CIN + c0;                              \
    const float* pb = xTb + (I).y * CIN + c0;                              \
    const float* pc = xTb + (I).z * CIN + c0;                              \
    const float* pd = xTb + (I).w * CIN + c0;                              \
    float4 A0 = *(const float4*)pa, A1 = *(const float4*)(pa + 4);         \
    float4 B0 = *(const float4*)pb, B1 = *(const float4*)(pb + 4);         \
    float4 C0 = *(const float4*)pc, C1 = *(const float4*)(pc + 4);         \
    float4 D0 = *(const float4*)pd, D1 = *(const float4*)(pd + 4);         \
    float* dst = xlds + (POS);                                             \
    dst[0 * 576] = (G).x*A0.x + (G).y*B0.x + (G).z*C0.x + (G).w*D0.x;      \
    dst[1 * 576] = (G).x*A0.y + (G).y*B0.y + (G).z*C0.y + (G).w*D0.y;      \
    dst[2 * 576] = (G).x*A0.z + (G).y*B0.z + (G).z*C0.z + (G).w*D0.z;      \
    dst[3 * 576] = (G).x*A0.w + (G).y*B0.w + (G).z*C0.w + (G).w*D0.w;      \
    dst[4 * 576] = (G).x*A1.x + (G).y*B1.x + (G).z*C1.x + (G).w*D1.x;      \
    dst[5 * 576] = (G).x*A1.y + (G).y*B1.y + (G).z*C1.y + (G).w*D1.y;      \
    dst[6 * 576] = (G).x*A1.z + (G).y*B1.z + (G).z*C1.z + (G).w*D1.z;      \
    dst[7 * 576] = (G).x*A1.w + (G).y*B1.w + (G).z*C1.w + (G).w*D1.w;      \
  }

  for (int cc = 0; cc < 8; ++cc) {
    const int c0 = cc * 8;
    __syncthreads();               // previous chunk fully consumed
    GATH(g0, i0, tid);
    GATH(g1, i1, tid + 256);
    if (has3) GATH(g2, i2, tid + 512);
    __syncthreads();
    // ---- GEMM: acc[k] += w[o=ow+k][cg][n] * xoff[cg][n][lane] ----
#pragma unroll
    for (int c = 0; c < 8; ++c) {
      const int cg = c0 + c;
#pragma unroll
      for (int n = 0; n < 9; ++n) {
        float xv = xlds[c * 576 + n * 64 + lane];
        const float* wr = wPu + (n * 64 + cg) * 128;   // wave-uniform addr
#pragma unroll
        for (int k = 0; k < 32; ++k)
          acc[k] = fmaf(wr[k], xv, acc[k]);
      }
    }
  }
#undef GATH

#pragma unroll
  for (int k = 0; k < 32; ++k) {
    out[((size_t)b * OC + ow_u + k) * HW + px0 + lane] = acc[k];
  }
}

extern "C" void kernel_launch(void* const* d_in, const int* in_sizes, int n_in,
                              void* d_out, int out_size, void* d_ws, size_t ws_size,
                              hipStream_t stream) {
  const float* x      = (const float*)d_in[0];  // (8,64,128,128)
  const float* w_conv = (const float*)d_in[1];  // (128,64,3,3)
  const float* w_p    = (const float*)d_in[2];  // (18,64,3,3)
  const float* b_p    = (const float*)d_in[3];  // (18,)
  float* outp = (float*)d_out;                  // (8,128,128,128)
  float* ws   = (float*)d_ws;                   // needs >= 52.8 MB

  float* wT   = ws + WT_OFF;
  float* wP   = ws + WP_OFF;
  float* offp = ws + OFF_OFF;
  float* xT   = ws + XT_OFF;

  repack_kernel<<<333, 256, 0, stream>>>(w_conv, w_p, wP, wT);
  transpose_kernel<<<dim3(256, 8), 256, 0, stream>>>(x, xT);
  offs_kernel<<<dim3(64, 8, 2), 256, 0, stream>>>(x, wT, offp);
  main_kernel<<<dim3(256, 8), 256, 0, stream>>>(xT, wP, offp, b_p, outp);
}